// Round 15
// baseline (78.482 us; speedup 1.0000x reference)
//
#include <hip/hip_runtime.h>
#include <hip/hip_cooperative_groups.h>
#include <hip/hip_fp16.h>
#include <math.h>

namespace cg = cooperative_groups;

#define HW 16384
#define NPROJ 100
#define NB 8
#define EPSV 1e-6f

__device__ inline float4 add4(float4 a, float4 b) {
    return make_float4(a.x + b.x, a.y + b.y, a.z + b.z, a.w + b.w);
}
__device__ inline float4 sub4(float4 a, float4 b) {
    return make_float4(a.x - b.x, a.y - b.y, a.z - b.z, a.w - b.w);
}
__device__ inline float4 shfl_up4(float4 v, int off) {
    return make_float4(__shfl_up(v.x, off), __shfl_up(v.y, off),
                       __shfl_up(v.z, off), __shfl_up(v.w, off));
}
__device__ inline float4 shfl_up4w(float4 v, int off, int w) {
    return make_float4(__shfl_up(v.x, off, w), __shfl_up(v.y, off, w),
                       __shfl_up(v.z, off, w), __shfl_up(v.w, off, w));
}
__device__ inline unsigned int packh2(float a, float b) {
    __half2 h = __floats2half2_rn(a, b);
    return *reinterpret_cast<unsigned int*>(&h);
}
__device__ inline float2 unpackh2(unsigned int w) {
    __half2 h = *reinterpret_cast<__half2*>(&w);
    return make_float2(__low2float(h), __high2float(h));
}

// Single cooperative kernel, 200 blocks x 1024 threads (1 block/CU at 86KB LDS;
// 200 <= 256 CUs so full co-residency for grid.sync).
// A: blocks 0..127 build per-(batch,sixteenth) partials (Xs=x0+x1+x2 store,
//    sum(Xs), sum(y0), ch0 max/argmax first-occurrence); block 0 zeroes out.
// sync. C: every block redoes the tiny 128-partial combine (16-lane shuffle
//    groups) and packs 82 contiguous pixels of Zh (fp16 x8, pixel-major 16B).
// B: prefix-table analytic ranksort into sidT (own position-half; ties skipped
//    when no d*r integral). sync. Phase 2: single-pass 8-channel register scan
//    (one 16B gather/pixel), CDF-difference integral, atomicAdd to out.
__global__ __launch_bounds__(1024)
__attribute__((amdgpu_waves_per_eu(4, 4)))
void fused_kernel(const float* __restrict__ X,
                  const float* __restrict__ Y,
                  const float* __restrict__ proj,
                  float* __restrict__ Xs,
                  uint4* __restrict__ Zh,
                  float* __restrict__ Pmax,
                  int* __restrict__ Pidx,
                  float* __restrict__ Psx,
                  float* __restrict__ Psy,
                  float* __restrict__ out) {
    __shared__ int ce[255];                     // c*2 | e
    __shared__ unsigned short Ptab[256 * 128];  // 64 KiB prefix table
    __shared__ int psum[8 * 128];               // packed (clsum<<5 | tiecnt)
    __shared__ unsigned short sidT[8192];       // 16 KiB own half
    __shared__ float4 lwa[17], lwb[17];
    __shared__ float lred[16];
    __shared__ float lmv[16], lsx[16], lsy[16];
    __shared__ int lmi[16];
    __shared__ float sInvX[8], sInvY[8], sFa[8];
    __shared__ int sFi[8];
    __shared__ int sBound;
    __shared__ int sAnyTie;

    cg::grid_group grid = cg::this_grid();
    const int bid = blockIdx.x;
    const int tid = threadIdx.x, lane = tid & 63, wid = tid >> 6;

    // ================= Step A: partials (blocks 0..127) =================
    if (bid == 0 && tid == 0) out[0] = 0.0f;
    if (bid < 128) {
        const int b = bid >> 4;
        const int p = (bid & 15) * 1024 + tid;
        const float* xb = X + (size_t)b * 3 * HW;
        float x0 = xb[p], x1 = xb[HW + p], x2 = xb[2 * HW + p];
        float y0 = Y[(size_t)b * 3 * HW + p];
        float s = x0 + x1 + x2;
        Xs[(size_t)b * HW + p] = s;
        float mv = x0;
        int mi = p;
        float sx = s, sy = y0;
#pragma unroll
        for (int off = 32; off > 0; off >>= 1) {
            float ov = __shfl_down(mv, off);
            int oi = __shfl_down(mi, off);
            sx += __shfl_down(sx, off);
            sy += __shfl_down(sy, off);
            if (ov > mv || (ov == mv && oi < mi)) { mv = ov; mi = oi; }
        }
        if (lane == 0) { lmv[wid] = mv; lmi[wid] = mi; lsx[wid] = sx; lsy[wid] = sy; }
        __syncthreads();
        if (tid == 0) {
            for (int w = 1; w < 16; ++w) {
                if (lmv[w] > lmv[0] || (lmv[w] == lmv[0] && lmi[w] < lmi[0])) {
                    lmv[0] = lmv[w];
                    lmi[0] = lmi[w];
                }
                lsx[0] += lsx[w];
                lsy[0] += lsy[w];
            }
            Pmax[bid] = lmv[0];
            Pidx[bid] = lmi[0];
            Psx[bid] = lsx[0];
            Psy[bid] = lsy[0];
        }
    }
    grid.sync();

    // ============ Step C: combine (redundant per block) + zprep ============
    if (tid < 128) {
        const int b = tid >> 4, k = tid & 15;
        float mv = Pmax[b * 16 + k];
        int mi = Pidx[b * 16 + k];
        float sx = Psx[b * 16 + k];
        float sy = Psy[b * 16 + k];
#pragma unroll
        for (int off = 8; off > 0; off >>= 1) {
            float ov = __shfl_down(mv, off, 16);
            int oi = __shfl_down(mi, off, 16);
            float osx = __shfl_down(sx, off, 16);
            float osy = __shfl_down(sy, off, 16);
            if (ov > mv || (ov == mv && oi < mi)) { mv = ov; mi = oi; }
            sx += osx;
            sy += osy;
        }
        if (k == 0) {
            float fa = (mv < EPSV) ? (EPSV - mv) : 0.0f;
            sFa[b] = fa;
            sFi[b] = mi;
            sInvX[b] = 1.0f / (sx + fa);
            sInvY[b] = 1.0f / sy;
        }
    }
    __syncthreads();
    {
        const int p = bid * 82 + tid;  // 200*82 = 16400 >= HW
        if (tid < 82 && p < HW) {
            float z[8];
#pragma unroll
            for (int b = 0; b < 8; ++b) {
                float s = Xs[(size_t)b * HW + p];
                if (p == sFi[b]) s += sFa[b];
                z[b] = s * sInvX[b] - Y[(size_t)b * 3 * HW + p] * sInvY[b];
            }
            Zh[p] = make_uint4(packh2(z[0], z[1]), packh2(z[2], z[3]),
                               packh2(z[4], z[5]), packh2(z[6], z[7]));
        }
    }

    // ================= Step B: prefix-table ranksort =================
    const int jp = bid >> 1;
    const int h = bid & 1;
    float a = proj[jp];
    float b = proj[NPROJ + jp];
    float inv = 1.0f / sqrtf(a * a + b * b);
    const float an = a * inv, bn = b * inv;
    const float ap = fabsf(an), bp = fabsf(bn);
    const bool flipi = (an < 0.0f), flipj = (bn < 0.0f);

    if (bp == 0.0f) {
        for (int t = tid; t < HW; t += 1024) {
            int i2 = t >> 7, j2 = t & 127;
            int ii = flipi ? 127 - i2 : i2;
            int jj = flipj ? 127 - j2 : j2;
            int idv = ii * 128 + jj;
            if (t == 8192) sBound = idv;
            int q = t - (h << 13);
            if ((unsigned)q < 8192u)
                sidT[(q & 7) * 1024 + (q >> 3)] = (unsigned short)idv;
        }
        __syncthreads();
    } else {
        if (tid == 0) sAnyTie = 0;
        if (tid < 255) {
            int d = tid - 127;
            double v = (double)d * ((double)ap / (double)bp);
            double cv = ceil(v);
            int e = (cv == v) ? 1 : 0;
            int c = (int)fmin(fmax(cv, -128.0), 129.0);
            ce[tid] = c * 2 + e;
            if (e && d >= 1) sAnyTie = 1;  // benign same-value race
        }
        __syncthreads();

        const int j2 = tid & 127;
        const int g = tid >> 7;
        const int jj = flipj ? 127 - j2 : j2;
        const bool anyTie = (sAnyTie != 0);

        int lp[32];
        int tmask = 0;
        {
            int run = 0;
            const int dd0 = g * 32;
#pragma unroll
            for (int q = 0; q < 32; ++q) {
                int dd = dd0 + q;
                int cl = 0;
                if (dd < 255) {
                    int c = ce[dd] >> 1;
                    cl = min(max(c + j2, 0), 128);
                }
                run += cl;
                lp[q] = run;
            }
            int tcnt = 0;
            if (anyTie) {
#pragma unroll
                for (int q = 1; q <= 16; ++q) {
                    int i2p = g * 16 + q;
                    if (i2p <= 127) {
                        int v = ce[i2p + 127];
                        if (v & 1) {
                            int tj = j2 + (v >> 1);
                            if (tj >= 0 && tj < 128) { tmask |= (1 << q); tcnt++; }
                        }
                    }
                }
            }
            psum[g * 128 + j2] = (run << 5) | tcnt;
        }
        __syncthreads();

        int carryP = 0, carryT = 0;
        for (int g2 = 0; g2 < g; ++g2) {
            int v = psum[g2 * 128 + j2];
            carryP += (v >> 5);
            carryT += (v & 31);
        }
        if (g == 0) Ptab[j2] = 0;
        {
            const int dd0 = g * 32;
#pragma unroll
            for (int q = 0; q < 32; ++q) {
                int dd = dd0 + q;
                if (dd < 255)
                    Ptab[(dd + 1) * 128 + j2] = (unsigned short)(carryP + lp[q]);
            }
        }
        __syncthreads();

        int tsum = carryT;
        const int i2s = g * 16;
#pragma unroll
        for (int q = 0; q < 16; ++q) {
            int i2 = i2s + q;
            if (q > 0) tsum += (tmask >> q) & 1;
            int wsum = (int)Ptab[(i2 + 128) * 128 + j2] - (int)Ptab[i2 * 128 + j2];
            int pos = wsum + tsum;
            int ii = flipi ? 127 - i2 : i2;
            int idv = ii * 128 + jj;
            if (pos == 8192) sBound = idv;
            int ql = pos - (h << 13);
            if ((unsigned)ql < 8192u)
                sidT[(ql & 7) * 1024 + (ql >> 3)] = (unsigned short)idv;
        }
        __syncthreads();
    }

    grid.sync();  // Zh fully written by all blocks

    // ================= Phase 2: scan + integral =================
    int ids[9];
#pragma unroll
    for (int m = 0; m < 8; ++m) ids[m] = (int)sidT[m * 1024 + tid];
    ids[8] = (tid < 1023) ? (int)sidT[tid + 1]
                          : ((h == 0) ? sBound : ids[7]);

    float dpc[8];
    {
        float pc_cur = (float)(ids[0] >> 7) * an + (float)(ids[0] & 127) * bn;
#pragma unroll
        for (int m = 0; m < 8; ++m) {
            int idn = ids[m + 1];
            float pc_nxt = (float)(idn >> 7) * an + (float)(idn & 127) * bn;
            dpc[m] = pc_nxt - pc_cur;
            pc_cur = pc_nxt;
        }
    }

    float4 zva[8], zvb[8];
#pragma unroll
    for (int m = 0; m < 8; ++m) {
        uint4 r = Zh[ids[m]];
        float2 f0 = unpackh2(r.x);
        float2 f1 = unpackh2(r.y);
        float2 f2 = unpackh2(r.z);
        float2 f3 = unpackh2(r.w);
        zva[m] = make_float4(f0.x, f0.y, f1.x, f1.y);
        zvb[m] = make_float4(f2.x, f2.y, f3.x, f3.y);
    }
#pragma unroll
    for (int m = 1; m < 8; ++m) {
        zva[m] = add4(zva[m], zva[m - 1]);
        zvb[m] = add4(zvb[m], zvb[m - 1]);
    }
    const float4 tota = zva[7], totb = zvb[7];

    float4 ia = tota, ib = totb;
#pragma unroll
    for (int off = 1; off < 64; off <<= 1) {
        float4 ua = shfl_up4(ia, off);
        float4 ub = shfl_up4(ib, off);
        if (lane >= off) { ia = add4(ia, ua); ib = add4(ib, ub); }
    }
    if (lane == 63) { lwa[wid] = ia; lwb[wid] = ib; }
    __syncthreads();
    if (tid < 16) {
        float4 va = lwa[tid], vb = lwb[tid];
        float4 sa = va, sb = vb;
#pragma unroll
        for (int off = 1; off < 16; off <<= 1) {
            float4 ua = shfl_up4w(sa, off, 16);
            float4 ub = shfl_up4w(sb, off, 16);
            if (tid >= off) { sa = add4(sa, ua); sb = add4(sb, ub); }
        }
        lwa[tid] = sub4(sa, va);
        lwb[tid] = sub4(sb, vb);
        if (tid == 15) { lwa[16] = sa; lwb[16] = sb; }
    }
    __syncthreads();

    float4 preA = add4(sub4(ia, tota), lwa[wid]);
    float4 preB = add4(sub4(ib, totb), lwb[wid]);
    if (h == 1) {
        preA = sub4(preA, lwa[16]);
        preB = sub4(preB, lwb[16]);
    }

    float acc = 0.0f;
#pragma unroll
    for (int m = 0; m < 8; ++m) {
        float4 cxa = add4(preA, zva[m]);
        float4 cxb = add4(preB, zvb[m]);
        float s8 = fabsf(cxa.x) + fabsf(cxa.y) + fabsf(cxa.z) + fabsf(cxa.w)
                 + fabsf(cxb.x) + fabsf(cxb.y) + fabsf(cxb.z) + fabsf(cxb.w);
        acc += s8 * dpc[m];
    }

#pragma unroll
    for (int off = 32; off > 0; off >>= 1) acc += __shfl_down(acc, off);
    if (lane == 0) lred[wid] = acc;
    __syncthreads();
    if (tid == 0) {
        float r = 0.0f;
        for (int w = 0; w < 16; ++w) r += lred[w];
        atomicAdd(out, r * (1.0f / NPROJ));
    }
}

extern "C" void kernel_launch(void* const* d_in, const int* in_sizes, int n_in,
                              void* d_out, int out_size, void* d_ws, size_t ws_size,
                              hipStream_t stream) {
    const float* X = (const float*)d_in[0];
    const float* Y = (const float*)d_in[1];
    const float* proj = (const float*)d_in[2];
    float* out = (float*)d_out;

    char* ws = (char*)d_ws;
    size_t off = 0;
    float* Xs = (float*)(ws + off);    off += (size_t)NB * HW * sizeof(float);
    uint4* Zh = (uint4*)(ws + off);    off += (size_t)HW * sizeof(uint4);
    float* Pmax = (float*)(ws + off);  off += 128 * sizeof(float);
    int* Pidx = (int*)(ws + off);      off += 128 * sizeof(int);
    float* Psx = (float*)(ws + off);   off += 128 * sizeof(float);
    float* Psy = (float*)(ws + off);   off += 128 * sizeof(float);

    void* args[] = {(void*)&X, (void*)&Y, (void*)&proj, (void*)&Xs, (void*)&Zh,
                    (void*)&Pmax, (void*)&Pidx, (void*)&Psx, (void*)&Psy,
                    (void*)&out};
    hipLaunchCooperativeKernel((void*)fused_kernel, dim3(NPROJ * 2), dim3(1024),
                               args, 0, stream);
}